// Round 3
// baseline (251.736 us; speedup 1.0000x reference)
//
#include <hip/hip_runtime.h>

#define EPS 1e-5f
// B=64, D=2048, E=64, H1=512, H2=256

typedef __attribute__((ext_vector_type(8))) short short8;
typedef __attribute__((ext_vector_type(4))) float f32x4;

__device__ __forceinline__ unsigned short f2bf(float f) {
  unsigned u = __float_as_uint(f);
  u = u + 0x7FFFu + ((u >> 16) & 1u);  // RNE
  return (unsigned short)(u >> 16);
}
__device__ __forceinline__ unsigned pack2(float a, float b) {
  return (unsigned)f2bf(a) | ((unsigned)f2bf(b) << 16);
}

// ================= prep =================
// blocks 0..255   : Qf/Rf (fp32, A-frag layout [cs:16][k:2048][32]) for 8 k each
// blocks 256..319 : W2f (bf16, B-frag layout [cs:16][o:256][32]), one h-octet per block
// block  320      : t2, c2
__global__ __launch_bounds__(256) void prep(
    const float* __restrict__ emb, const float* __restrict__ W1,
    const float* __restrict__ g1, const float* __restrict__ v1,
    const float* __restrict__ W2,
    const float* __restrict__ g2, const float* __restrict__ v2,
    const float* __restrict__ b2, const float* __restrict__ m2,
    const float* __restrict__ beta2,
    float* __restrict__ Qf, float* __restrict__ Rf,
    unsigned short* __restrict__ W2f,
    float* __restrict__ t2, float* __restrict__ c2) {
  const int x = blockIdx.x, t = threadIdx.x;
  if (x < 256) {
    const int k0 = x * 8;
    const int h = t * 2;
    const float a0 = g1[h] * rsqrtf(v1[h] + EPS);
    const float a1 = g1[h + 1] * rsqrtf(v1[h + 1] + EPS);
    const float* We = W1 + 2048 * 512;
    float acc0[8], acc1[8];
    #pragma unroll
    for (int k = 0; k < 8; ++k) { acc0[k] = 0.f; acc1[k] = 0.f; }
    for (int e = 0; e < 64; ++e) {
      float2 wv = *(const float2*)(We + e * 512 + h);
      #pragma unroll
      for (int k = 0; k < 8; ++k) {
        float ev = emb[(k0 + k) * 64 + e];  // block/wave-uniform
        acc0[k] = fmaf(ev, wv.x, acc0[k]);
        acc1[k] = fmaf(ev, wv.y, acc1[k]);
      }
    }
    const int cs = h >> 5;       // 0..15
    const int rm = h & 31;       // 0,2,..,30
    #pragma unroll
    for (int k = 0; k < 8; ++k) {
      const int kk = k0 + k;
      *(float2*)(Qf + cs * 65536 + kk * 32 + rm) = make_float2(a0 * acc0[k], a1 * acc1[k]);
      float2 wv = *(const float2*)(W1 + (size_t)kk * 512 + h);
      *(float2*)(Rf + cs * 65536 + kk * 32 + rm) = make_float2(a0 * wv.x, a1 * wv.y);
    }
  } else if (x < 320) {
    const int h0 = (x - 256) * 8;  // h-octet
    const int o = t;
    unsigned d[4];
    #pragma unroll
    for (int i = 0; i < 4; ++i) {
      float v0 = W2[(h0 + 2 * i) * 256 + o];       // coalesced over o
      float v1_ = W2[(h0 + 2 * i + 1) * 256 + o];
      d[i] = pack2(v0, v1_);
    }
    const int cs = h0 >> 5;
    const int rm = h0 & 31;
    *(uint4*)(W2f + cs * 8192 + o * 32 + rm) = make_uint4(d[0], d[1], d[2], d[3]);
  } else {
    float tv = g2[t] * rsqrtf(v2[t] + EPS);
    t2[t] = tv;
    c2[t] = tv * (b2[t] - m2[t]) + beta2[t];
  }
}

// ================= Pf = fp32 A-frag layout of a1*(rep@W1d) + pbias =================
// one block per b; 1024 thr = 16 k-slices x 64 h-octet lanes; LDS reduce.
__global__ __launch_bounds__(1024) void p_gemm(
    const float* __restrict__ rep, const float* __restrict__ W1,
    const float* __restrict__ g1, const float* __restrict__ v1,
    const float* __restrict__ b1, const float* __restrict__ m1,
    const float* __restrict__ beta1,
    float* __restrict__ Pf) {
  __shared__ float red[16 * 512];
  const int b = blockIdx.x, t = threadIdx.x;
  const int lane = t & 63, kq = t >> 6;
  const int h = lane * 8;
  const float* wp = W1 + (size_t)(kq * 128) * 512 + h;
  const float* rp = rep + b * 2048 + kq * 128;
  float acc[8];
  #pragma unroll
  for (int i = 0; i < 8; ++i) acc[i] = 0.f;
  #pragma unroll 4
  for (int k = 0; k < 128; ++k) {
    f32x4 wa = *(const f32x4*)(wp + (size_t)k * 512);
    f32x4 wb = *(const f32x4*)(wp + (size_t)k * 512 + 4);
    float rk = rp[k];  // wave-uniform
    acc[0] = fmaf(rk, wa[0], acc[0]); acc[1] = fmaf(rk, wa[1], acc[1]);
    acc[2] = fmaf(rk, wa[2], acc[2]); acc[3] = fmaf(rk, wa[3], acc[3]);
    acc[4] = fmaf(rk, wb[0], acc[4]); acc[5] = fmaf(rk, wb[1], acc[5]);
    acc[6] = fmaf(rk, wb[2], acc[6]); acc[7] = fmaf(rk, wb[3], acc[7]);
  }
  *(f32x4*)(&red[kq * 512 + h])     = (f32x4){acc[0], acc[1], acc[2], acc[3]};
  *(f32x4*)(&red[kq * 512 + h + 4]) = (f32x4){acc[4], acc[5], acc[6], acc[7]};
  __syncthreads();
  if (t < 512) {
    const int hh = t;
    float tot = 0.f;
    #pragma unroll
    for (int q = 0; q < 16; ++q) tot += red[q * 512 + hh];
    float a = g1[hh] * rsqrtf(v1[hh] + EPS);
    float val = fmaf(a, tot, fmaf(a, b1[hh] - m1[hh], beta1[hh]));
    Pf[(hh >> 5) * 2048 + b * 32 + (hh & 31)] = val;
  }
}

// ================= fused main =================
// Block: 2 k x 64 b = 128 rows, N=256 o, K=512. No LDS in K-loop, no barriers:
// A-frags computed in registers from frag-ordered fp32 Pf/Qf/Rf; B-frags are
// single coalesced 1KB loads from frag-ordered W2f. Wave-tile M=128 x N=64.
__device__ __forceinline__ short8 make_frag(f32x4 pa, f32x4 pb,
                                            f32x4 qa, f32x4 qb,
                                            f32x4 ra, f32x4 rb_, float rb) {
  unsigned u[8];
  #pragma unroll
  for (int j = 0; j < 4; ++j) {
    float z0 = fmaf(-rb, ra[j], pa[j] + qa[j]);
    float z1 = fmaf(-rb, rb_[j], pb[j] + qb[j]);
    z0 = fmaxf(z0, 0.f);
    z1 = fmaxf(z1, 0.f);
    u[j] = __float_as_uint(z0) + 0x8000u;      // round-half-up bias
    u[j + 4] = __float_as_uint(z1) + 0x8000u;
  }
  short8 f;
  unsigned* fp = (unsigned*)&f;
  fp[0] = __builtin_amdgcn_perm(u[1], u[0], 0x07060302);  // (hi,lo) -> packed bf16x2
  fp[1] = __builtin_amdgcn_perm(u[3], u[2], 0x07060302);
  fp[2] = __builtin_amdgcn_perm(u[5], u[4], 0x07060302);
  fp[3] = __builtin_amdgcn_perm(u[7], u[6], 0x07060302);
  return f;
}

__global__ __launch_bounds__(256, 2) void fused_main(
    const float* __restrict__ rep,
    const float* __restrict__ Pf,
    const float* __restrict__ Qf,
    const float* __restrict__ Rf,
    const unsigned short* __restrict__ W2f,
    const float* __restrict__ t2, const float* __restrict__ c2,
    const float* __restrict__ W3, const float* __restrict__ b3,
    float* __restrict__ out) {
  __shared__ float partial[4][128];
  const int t = threadIdx.x;
  const int w = t >> 6;
  const int ln = t & 15;
  const int lq = (t >> 4) & 3;
  const int lqo = lq * 8;
  const int k0 = blockIdx.x * 2;

  // rep[b][k0], rep[b][k0+1] for the 4 b-groups this lane touches
  float rbA[4], rbB[4];
  #pragma unroll
  for (int pg = 0; pg < 4; ++pg) {
    float2 rv = *(const float2*)(rep + (pg * 16 + ln) * 2048 + k0);
    rbA[pg] = rv.x;
    rbB[pg] = rv.y;
  }

  f32x4 acc[8][4];
  #pragma unroll
  for (int mi = 0; mi < 8; ++mi)
    #pragma unroll
    for (int nj = 0; nj < 4; ++nj) acc[mi][nj] = (f32x4){0.f, 0.f, 0.f, 0.f};

  for (int c = 0; c < 8; ++c) {
    #pragma unroll
    for (int ks = 0; ks < 2; ++ks) {
      const int cs = c * 2 + ks;
      // Q/R for the block's two k values: lq-broadcast 16B loads
      const float* qb = Qf + cs * 65536 + k0 * 32 + lqo;
      const float* rp = Rf + cs * 65536 + k0 * 32 + lqo;
      f32x4 q0a = *(const f32x4*)(qb);      f32x4 q0b = *(const f32x4*)(qb + 4);
      f32x4 q1a = *(const f32x4*)(qb + 32); f32x4 q1b = *(const f32x4*)(qb + 36);
      f32x4 r0a = *(const f32x4*)(rp);      f32x4 r0b = *(const f32x4*)(rp + 4);
      f32x4 r1a = *(const f32x4*)(rp + 32); f32x4 r1b = *(const f32x4*)(rp + 36);
      // B-frags: fully coalesced 1KB wave loads
      const unsigned short* wb = W2f + cs * 8192 + (w * 64 + ln) * 32 + lqo;
      short8 bfr[4];
      #pragma unroll
      for (int nj = 0; nj < 4; ++nj) bfr[nj] = *(const short8*)(wb + nj * 512);
      // A-frags per b-group; mi=pg uses k0, mi=pg+4 uses k0+1 (same P-frag)
      const float* pb = Pf + cs * 2048 + ln * 32 + lqo;
      #pragma unroll
      for (int pg = 0; pg < 4; ++pg) {
        f32x4 pa = *(const f32x4*)(pb + pg * 512);
        f32x4 pc = *(const f32x4*)(pb + pg * 512 + 4);
        short8 afr = make_frag(pa, pc, q0a, q0b, r0a, r0b, rbA[pg]);
        #pragma unroll
        for (int nj = 0; nj < 4; ++nj)
          acc[pg][nj] = __builtin_amdgcn_mfma_f32_16x16x32_bf16(afr, bfr[nj], acc[pg][nj], 0, 0, 0);
        afr = make_frag(pa, pc, q1a, q1b, r1a, r1b, rbB[pg]);
        #pragma unroll
        for (int nj = 0; nj < 4; ++nj)
          acc[pg + 4][nj] = __builtin_amdgcn_mfma_f32_16x16x32_bf16(afr, bfr[nj], acc[pg + 4][nj], 0, 0, 0);
      }
    }
  }

  // epilogue: u = relu(t2[o]*acc + c2[o]) * W3[o]; reduce over o
  float t2v[4], c2v[4], w3v[4];
  #pragma unroll
  for (int nj = 0; nj < 4; ++nj) {
    int o = w * 64 + nj * 16 + ln;
    t2v[nj] = t2[o];
    c2v[nj] = c2[o];
    w3v[nj] = W3[o];
  }
  #pragma unroll
  for (int mi = 0; mi < 8; ++mi) {
    float s[4] = {0.f, 0.f, 0.f, 0.f};
    #pragma unroll
    for (int nj = 0; nj < 4; ++nj)
      #pragma unroll
      for (int r = 0; r < 4; ++r) {
        float u = fmaf(t2v[nj], acc[mi][nj][r], c2v[nj]);
        u = fmaxf(u, 0.f);
        s[r] = fmaf(u, w3v[nj], s[r]);
      }
    #pragma unroll
    for (int r = 0; r < 4; ++r) {
      #pragma unroll
      for (int m = 1; m < 16; m <<= 1) s[r] += __shfl_xor(s[r], m, 64);
    }
    if (ln == 0) {
      #pragma unroll
      for (int r = 0; r < 4; ++r) partial[w][mi * 16 + lq * 4 + r] = s[r];
    }
  }
  __syncthreads();
  if (t < 128) {
    out[(t & 63) * 2048 + k0 + (t >> 6)] =
        partial[0][t] + partial[1][t] + partial[2][t] + partial[3][t] + b3[0];
  }
}

extern "C" void kernel_launch(void* const* d_in, const int* in_sizes, int n_in,
                              void* d_out, int out_size, void* d_ws, size_t ws_size,
                              hipStream_t stream) {
  const float* rep   = (const float*)d_in[0];
  const float* emb   = (const float*)d_in[1];
  const float* W1    = (const float*)d_in[2];
  const float* b1    = (const float*)d_in[3];
  const float* g1    = (const float*)d_in[4];
  const float* beta1 = (const float*)d_in[5];
  const float* m1    = (const float*)d_in[6];
  const float* v1    = (const float*)d_in[7];
  const float* W2    = (const float*)d_in[8];
  const float* b2    = (const float*)d_in[9];
  const float* g2    = (const float*)d_in[10];
  const float* beta2 = (const float*)d_in[11];
  const float* m2    = (const float*)d_in[12];
  const float* v2    = (const float*)d_in[13];
  const float* W3    = (const float*)d_in[14];
  const float* b3    = (const float*)d_in[15];
  float* out = (float*)d_out;

  char* ws = (char*)d_ws;
  float* t2           = (float*)(ws + 0);        // 256 f32
  float* c2           = (float*)(ws + 1024);     // 256 f32
  float* Pf           = (float*)(ws + 4096);     // 16x64x32 f32 = 128 KB
  float* Qf           = (float*)(ws + 262144);   // 16x2048x32 f32 = 4 MB
  float* Rf           = (float*)(ws + 4456448);  // 4 MB
  unsigned short* W2f = (unsigned short*)(ws + 8650752);  // 16x256x32 bf16 = 256 KB

  prep<<<321, 256, 0, stream>>>(emb, W1, g1, v1, W2, g2, v2, b2, m2, beta2,
                                Qf, Rf, W2f, t2, c2);
  p_gemm<<<64, 1024, 0, stream>>>(rep, W1, g1, v1, b1, m1, beta1, Pf);
  fused_main<<<1024, 256, 0, stream>>>(rep, Pf, Qf, Rf, W2f, t2, c2, W3, b3, out);
}

// Round 4
// 213.740 us; speedup vs baseline: 1.1778x; 1.1778x over previous
//
#include <hip/hip_runtime.h>

#define EPS 1e-5f
// B=64, D=2048, E=64, H1=512, H2=256

typedef __attribute__((ext_vector_type(8))) short short8;
typedef __attribute__((ext_vector_type(4))) float f32x4;

__device__ __forceinline__ unsigned short f2bf(float f) {
  unsigned u = __float_as_uint(f);
  u = u + 0x7FFFu + ((u >> 16) & 1u);  // RNE
  return (unsigned short)(u >> 16);
}
__device__ __forceinline__ unsigned pack2(float a, float b) {
  return (unsigned)f2bf(a) | ((unsigned)f2bf(b) << 16);
}

// ================= prep =================
// blocks 0..255   : Qf/Rf (fp32, A-frag layout [cs:16][k:2048][32]) for 8 k each
// blocks 256..319 : W2f (bf16, B-frag layout [cs:16][o:256][32]), one h-octet per block
// block  320      : t2, c2
__global__ __launch_bounds__(256) void prep(
    const float* __restrict__ emb, const float* __restrict__ W1,
    const float* __restrict__ g1, const float* __restrict__ v1,
    const float* __restrict__ W2,
    const float* __restrict__ g2, const float* __restrict__ v2,
    const float* __restrict__ b2, const float* __restrict__ m2,
    const float* __restrict__ beta2,
    float* __restrict__ Qf, float* __restrict__ Rf,
    unsigned short* __restrict__ W2f,
    float* __restrict__ t2, float* __restrict__ c2) {
  const int x = blockIdx.x, t = threadIdx.x;
  if (x < 256) {
    const int k0 = x * 8;
    const int h = t * 2;
    const float a0 = g1[h] * rsqrtf(v1[h] + EPS);
    const float a1 = g1[h + 1] * rsqrtf(v1[h + 1] + EPS);
    const float* We = W1 + 2048 * 512;
    float acc0[8], acc1[8];
    #pragma unroll
    for (int k = 0; k < 8; ++k) { acc0[k] = 0.f; acc1[k] = 0.f; }
    for (int e = 0; e < 64; ++e) {
      float2 wv = *(const float2*)(We + e * 512 + h);
      #pragma unroll
      for (int k = 0; k < 8; ++k) {
        float ev = emb[(k0 + k) * 64 + e];  // block-uniform
        acc0[k] = fmaf(ev, wv.x, acc0[k]);
        acc1[k] = fmaf(ev, wv.y, acc1[k]);
      }
    }
    const int cs = h >> 5;
    const int rm = h & 31;
    #pragma unroll
    for (int k = 0; k < 8; ++k) {
      const int kk = k0 + k;
      *(float2*)(Qf + cs * 65536 + kk * 32 + rm) = make_float2(a0 * acc0[k], a1 * acc1[k]);
      float2 wv = *(const float2*)(W1 + (size_t)kk * 512 + h);
      *(float2*)(Rf + cs * 65536 + kk * 32 + rm) = make_float2(a0 * wv.x, a1 * wv.y);
    }
  } else if (x < 320) {
    const int h0 = (x - 256) * 8;
    const int o = t;
    unsigned d[4];
    #pragma unroll
    for (int i = 0; i < 4; ++i) {
      float v0 = W2[(h0 + 2 * i) * 256 + o];
      float v1_ = W2[(h0 + 2 * i + 1) * 256 + o];
      d[i] = pack2(v0, v1_);
    }
    const int cs = h0 >> 5;
    const int rm = h0 & 31;
    *(uint4*)(W2f + cs * 8192 + o * 32 + rm) = make_uint4(d[0], d[1], d[2], d[3]);
  } else {
    float tv = g2[t] * rsqrtf(v2[t] + EPS);
    t2[t] = tv;
    c2[t] = tv * (b2[t] - m2[t]) + beta2[t];
  }
}

// ================= Pf = fp32 A-frag layout of a1*(rep@W1d) + pbias =================
__global__ __launch_bounds__(1024) void p_gemm(
    const float* __restrict__ rep, const float* __restrict__ W1,
    const float* __restrict__ g1, const float* __restrict__ v1,
    const float* __restrict__ b1, const float* __restrict__ m1,
    const float* __restrict__ beta1,
    float* __restrict__ Pf) {
  __shared__ float red[16 * 512];
  const int b = blockIdx.x, t = threadIdx.x;
  const int lane = t & 63, kq = t >> 6;
  const int h = lane * 8;
  const float* wp = W1 + (size_t)(kq * 128) * 512 + h;
  const float* rp = rep + b * 2048 + kq * 128;
  float acc[8];
  #pragma unroll
  for (int i = 0; i < 8; ++i) acc[i] = 0.f;
  #pragma unroll 4
  for (int k = 0; k < 128; ++k) {
    f32x4 wa = *(const f32x4*)(wp + (size_t)k * 512);
    f32x4 wb = *(const f32x4*)(wp + (size_t)k * 512 + 4);
    float rk = rp[k];  // wave-uniform
    acc[0] = fmaf(rk, wa[0], acc[0]); acc[1] = fmaf(rk, wa[1], acc[1]);
    acc[2] = fmaf(rk, wa[2], acc[2]); acc[3] = fmaf(rk, wa[3], acc[3]);
    acc[4] = fmaf(rk, wb[0], acc[4]); acc[5] = fmaf(rk, wb[1], acc[5]);
    acc[6] = fmaf(rk, wb[2], acc[6]); acc[7] = fmaf(rk, wb[3], acc[7]);
  }
  *(f32x4*)(&red[kq * 512 + h])     = (f32x4){acc[0], acc[1], acc[2], acc[3]};
  *(f32x4*)(&red[kq * 512 + h + 4]) = (f32x4){acc[4], acc[5], acc[6], acc[7]};
  __syncthreads();
  if (t < 512) {
    const int hh = t;
    float tot = 0.f;
    #pragma unroll
    for (int q = 0; q < 16; ++q) tot += red[q * 512 + hh];
    float a = g1[hh] * rsqrtf(v1[hh] + EPS);
    float val = fmaf(a, tot, fmaf(a, b1[hh] - m1[hh], beta1[hh]));
    Pf[(hh >> 5) * 2048 + b * 32 + (hh & 31)] = val;
  }
}

// ================= fused main =================
// Block: 1 k x 64 b (M=64), N=256, K=512 in 16 chunks of 32.
// LDS-shared A-gen (1x redundancy): each thread computes exactly one 16B frag
// group per chunk (3 coalesced f32x8 loads), writes one linear ds_write_b128.
// Double-buffered A, one barrier/chunk. B-frags: contiguous 1KB loads from
// frag-ordered W2f, issued BEFORE the barrier to overlap latency.
// Wave-tile 64x64 -> acc[4][4]=64 regs -> 3 waves/SIMD occupancy.
__global__ __launch_bounds__(256, 3) void fused_main(
    const float* __restrict__ rep,
    const float* __restrict__ Pf,
    const float* __restrict__ Qf,
    const float* __restrict__ Rf,
    const unsigned short* __restrict__ W2f,
    const float* __restrict__ t2, const float* __restrict__ c2,
    const float* __restrict__ W3, const float* __restrict__ b3,
    float* __restrict__ out) {
  __shared__ unsigned short Abuf[2][2048];  // 2 x 4KB, frag-ordered
  __shared__ float partial[4][64];

  const int t = threadIdx.x;
  const int w = t >> 6;
  const int ln = t & 15;
  const int lq = (t >> 4) & 3;
  const int k0 = blockIdx.x;

  // gen role: this thread owns A rows b=w*16+ln, cols lq*8..lq*8+7 of each chunk
  const int bg = w * 16 + ln;
  const float rb = rep[bg * 2048 + k0];
  const float* pbase = Pf + bg * 32 + lq * 8;
  const float* qbase = Qf + k0 * 32 + lq * 8;
  const float* rbase = Rf + k0 * 32 + lq * 8;

  f32x4 acc[4][4];
  #pragma unroll
  for (int mi = 0; mi < 4; ++mi)
    #pragma unroll
    for (int nj = 0; nj < 4; ++nj) acc[mi][nj] = (f32x4){0.f, 0.f, 0.f, 0.f};

  auto gen = [&](int cs, int bi) {
    f32x4 pa = *(const f32x4*)(pbase + cs * 2048);
    f32x4 pb = *(const f32x4*)(pbase + cs * 2048 + 4);
    f32x4 qa = *(const f32x4*)(qbase + cs * 65536);
    f32x4 qb = *(const f32x4*)(qbase + cs * 65536 + 4);
    f32x4 ra = *(const f32x4*)(rbase + cs * 65536);
    f32x4 rc = *(const f32x4*)(rbase + cs * 65536 + 4);
    unsigned u[8];
    #pragma unroll
    for (int j = 0; j < 4; ++j) {
      float z0 = fmaf(-rb, ra[j], pa[j] + qa[j]);
      float z1 = fmaf(-rb, rc[j], pb[j] + qb[j]);
      u[j]     = __float_as_uint(fmaxf(z0, 0.f)) + 0x8000u;
      u[j + 4] = __float_as_uint(fmaxf(z1, 0.f)) + 0x8000u;
    }
    unsigned d0 = __builtin_amdgcn_perm(u[1], u[0], 0x07060302);
    unsigned d1 = __builtin_amdgcn_perm(u[3], u[2], 0x07060302);
    unsigned d2 = __builtin_amdgcn_perm(u[5], u[4], 0x07060302);
    unsigned d3 = __builtin_amdgcn_perm(u[7], u[6], 0x07060302);
    *(uint4*)(&Abuf[bi][t * 8]) = make_uint4(d0, d1, d2, d3);  // linear b128
  };

  const unsigned short* wbase = W2f + (w * 64 + ln) * 32 + lq * 8;

  gen(0, 0);

  for (int cs = 0; cs < 16; ++cs) {
    // B-frags for this chunk: contiguous 1KB wave loads; issue before barrier
    short8 bfr[4];
    #pragma unroll
    for (int nj = 0; nj < 4; ++nj)
      bfr[nj] = *(const short8*)(wbase + cs * 8192 + nj * 512);
    __syncthreads();
    if (cs < 15) gen(cs + 1, (cs + 1) & 1);
    const unsigned short* ab = Abuf[cs & 1];
    short8 afr[4];
    #pragma unroll
    for (int mi = 0; mi < 4; ++mi)
      afr[mi] = *(const short8*)(ab + ((mi * 4 + lq) * 16 + ln) * 8);
    #pragma unroll
    for (int mi = 0; mi < 4; ++mi)
      #pragma unroll
      for (int nj = 0; nj < 4; ++nj)
        acc[mi][nj] = __builtin_amdgcn_mfma_f32_16x16x32_bf16(afr[mi], bfr[nj], acc[mi][nj], 0, 0, 0);
  }

  // epilogue: u = relu(t2[o]*acc + c2[o]) * W3[o]; reduce over o
  float t2v[4], c2v[4], w3v[4];
  #pragma unroll
  for (int nj = 0; nj < 4; ++nj) {
    int o = w * 64 + nj * 16 + ln;
    t2v[nj] = t2[o];
    c2v[nj] = c2[o];
    w3v[nj] = W3[o];
  }
  #pragma unroll
  for (int mi = 0; mi < 4; ++mi) {
    float s[4] = {0.f, 0.f, 0.f, 0.f};
    #pragma unroll
    for (int nj = 0; nj < 4; ++nj)
      #pragma unroll
      for (int r = 0; r < 4; ++r) {
        float u = fmaf(t2v[nj], acc[mi][nj][r], c2v[nj]);
        u = fmaxf(u, 0.f);
        s[r] = fmaf(u, w3v[nj], s[r]);
      }
    #pragma unroll
    for (int r = 0; r < 4; ++r) {
      #pragma unroll
      for (int m = 1; m < 16; m <<= 1) s[r] += __shfl_xor(s[r], m, 64);
    }
    if (ln == 0) {
      #pragma unroll
      for (int r = 0; r < 4; ++r) partial[w][mi * 16 + lq * 4 + r] = s[r];
    }
  }
  __syncthreads();
  if (t < 64) {
    out[t * 2048 + k0] =
        partial[0][t] + partial[1][t] + partial[2][t] + partial[3][t] + b3[0];
  }
}

extern "C" void kernel_launch(void* const* d_in, const int* in_sizes, int n_in,
                              void* d_out, int out_size, void* d_ws, size_t ws_size,
                              hipStream_t stream) {
  const float* rep   = (const float*)d_in[0];
  const float* emb   = (const float*)d_in[1];
  const float* W1    = (const float*)d_in[2];
  const float* b1    = (const float*)d_in[3];
  const float* g1    = (const float*)d_in[4];
  const float* beta1 = (const float*)d_in[5];
  const float* m1    = (const float*)d_in[6];
  const float* v1    = (const float*)d_in[7];
  const float* W2    = (const float*)d_in[8];
  const float* b2    = (const float*)d_in[9];
  const float* g2    = (const float*)d_in[10];
  const float* beta2 = (const float*)d_in[11];
  const float* m2    = (const float*)d_in[12];
  const float* v2    = (const float*)d_in[13];
  const float* W3    = (const float*)d_in[14];
  const float* b3    = (const float*)d_in[15];
  float* out = (float*)d_out;

  char* ws = (char*)d_ws;
  float* t2           = (float*)(ws + 0);        // 256 f32
  float* c2           = (float*)(ws + 1024);     // 256 f32
  float* Pf           = (float*)(ws + 4096);     // 16x64x32 f32 = 128 KB
  float* Qf           = (float*)(ws + 262144);   // 16x2048x32 f32 = 4 MB
  float* Rf           = (float*)(ws + 4456448);  // 4 MB
  unsigned short* W2f = (unsigned short*)(ws + 8650752);  // 16x256x32 bf16 = 256 KB

  prep<<<321, 256, 0, stream>>>(emb, W1, g1, v1, W2, g2, v2, b2, m2, beta2,
                                Qf, Rf, W2f, t2, c2);
  p_gemm<<<64, 1024, 0, stream>>>(rep, W1, g1, v1, b1, m1, beta1, Pf);
  fused_main<<<2048, 256, 0, stream>>>(rep, Pf, Qf, Rf, W2f, t2, c2, W3, b3, out);
}

// Round 5
// 199.779 us; speedup vs baseline: 1.2601x; 1.0699x over previous
//
#include <hip/hip_runtime.h>

#define EPS 1e-5f
// B=64, D=2048, E=64, H1=512, H2=256

typedef __attribute__((ext_vector_type(8))) short short8;
typedef __attribute__((ext_vector_type(4))) float f32x4;

__device__ __forceinline__ unsigned short f2bf(float f) {
  unsigned u = __float_as_uint(f);
  u = u + 0x7FFFu + ((u >> 16) & 1u);  // RNE
  return (unsigned short)(u >> 16);
}
__device__ __forceinline__ unsigned pack2(float a, float b) {
  return (unsigned)f2bf(a) | ((unsigned)f2bf(b) << 16);
}

// ================= prep =================
// blocks 0..255   : Qf/Rf (fp32, A-frag layout [cs:16][k:2048][32]) for 8 k each
// blocks 256..319 : W2f (bf16, B-frag layout [cs:16][o:256][32]), one h-octet per block
// block  320      : t2, c2
__global__ __launch_bounds__(256) void prep(
    const float* __restrict__ emb, const float* __restrict__ W1,
    const float* __restrict__ g1, const float* __restrict__ v1,
    const float* __restrict__ W2,
    const float* __restrict__ g2, const float* __restrict__ v2,
    const float* __restrict__ b2, const float* __restrict__ m2,
    const float* __restrict__ beta2,
    float* __restrict__ Qf, float* __restrict__ Rf,
    unsigned short* __restrict__ W2f,
    float* __restrict__ t2, float* __restrict__ c2) {
  const int x = blockIdx.x, t = threadIdx.x;
  if (x < 256) {
    const int k0 = x * 8;
    const int h = t * 2;
    const float a0 = g1[h] * rsqrtf(v1[h] + EPS);
    const float a1 = g1[h + 1] * rsqrtf(v1[h + 1] + EPS);
    const float* We = W1 + 2048 * 512;
    float acc0[8], acc1[8];
    #pragma unroll
    for (int k = 0; k < 8; ++k) { acc0[k] = 0.f; acc1[k] = 0.f; }
    for (int e = 0; e < 64; ++e) {
      float2 wv = *(const float2*)(We + e * 512 + h);
      #pragma unroll
      for (int k = 0; k < 8; ++k) {
        float ev = emb[(k0 + k) * 64 + e];  // block-uniform
        acc0[k] = fmaf(ev, wv.x, acc0[k]);
        acc1[k] = fmaf(ev, wv.y, acc1[k]);
      }
    }
    const int cs = h >> 5;
    const int rm = h & 31;
    #pragma unroll
    for (int k = 0; k < 8; ++k) {
      const int kk = k0 + k;
      *(float2*)(Qf + cs * 65536 + kk * 32 + rm) = make_float2(a0 * acc0[k], a1 * acc1[k]);
      float2 wv = *(const float2*)(W1 + (size_t)kk * 512 + h);
      *(float2*)(Rf + cs * 65536 + kk * 32 + rm) = make_float2(a0 * wv.x, a1 * wv.y);
    }
  } else if (x < 320) {
    const int h0 = (x - 256) * 8;
    const int o = t;
    unsigned d[4];
    #pragma unroll
    for (int i = 0; i < 4; ++i) {
      float v0 = W2[(h0 + 2 * i) * 256 + o];
      float v1_ = W2[(h0 + 2 * i + 1) * 256 + o];
      d[i] = pack2(v0, v1_);
    }
    const int cs = h0 >> 5;
    const int rm = h0 & 31;
    *(uint4*)(W2f + cs * 8192 + o * 32 + rm) = make_uint4(d[0], d[1], d[2], d[3]);
  } else {
    float tv = g2[t] * rsqrtf(v2[t] + EPS);
    t2[t] = tv;
    c2[t] = tv * (b2[t] - m2[t]) + beta2[t];
  }
}

// ================= Pf = fp32 A-frag layout of a1*(rep@W1d) + pbias =================
__global__ __launch_bounds__(1024) void p_gemm(
    const float* __restrict__ rep, const float* __restrict__ W1,
    const float* __restrict__ g1, const float* __restrict__ v1,
    const float* __restrict__ b1, const float* __restrict__ m1,
    const float* __restrict__ beta1,
    float* __restrict__ Pf) {
  __shared__ float red[16 * 512];
  const int b = blockIdx.x, t = threadIdx.x;
  const int lane = t & 63, kq = t >> 6;
  const int h = lane * 8;
  const float* wp = W1 + (size_t)(kq * 128) * 512 + h;
  const float* rp = rep + b * 2048 + kq * 128;
  float acc[8];
  #pragma unroll
  for (int i = 0; i < 8; ++i) acc[i] = 0.f;
  #pragma unroll 4
  for (int k = 0; k < 128; ++k) {
    f32x4 wa = *(const f32x4*)(wp + (size_t)k * 512);
    f32x4 wb = *(const f32x4*)(wp + (size_t)k * 512 + 4);
    float rk = rp[k];  // wave-uniform
    acc[0] = fmaf(rk, wa[0], acc[0]); acc[1] = fmaf(rk, wa[1], acc[1]);
    acc[2] = fmaf(rk, wa[2], acc[2]); acc[3] = fmaf(rk, wa[3], acc[3]);
    acc[4] = fmaf(rk, wb[0], acc[4]); acc[5] = fmaf(rk, wb[1], acc[5]);
    acc[6] = fmaf(rk, wb[2], acc[6]); acc[7] = fmaf(rk, wb[3], acc[7]);
  }
  *(f32x4*)(&red[kq * 512 + h])     = (f32x4){acc[0], acc[1], acc[2], acc[3]};
  *(f32x4*)(&red[kq * 512 + h + 4]) = (f32x4){acc[4], acc[5], acc[6], acc[7]};
  __syncthreads();
  if (t < 512) {
    const int hh = t;
    float tot = 0.f;
    #pragma unroll
    for (int q = 0; q < 16; ++q) tot += red[q * 512 + hh];
    float a = g1[hh] * rsqrtf(v1[hh] + EPS);
    float val = fmaf(a, tot, fmaf(a, b1[hh] - m1[hh], beta1[hh]));
    Pf[(hh >> 5) * 2048 + b * 32 + (hh & 31)] = val;
  }
}

// ================= fused main (software-pipelined) =================
// Block: 1 k x 64 b (M=64), N=256, K=512 in 16 chunks of 32.
// Q/R rows (block-uniform in k0) preloaded to LDS once. P inputs register-
// pipelined 2 chunks ahead (global L2 latency off critical path). B-frags
// double-buffered in regs, 1 chunk ahead. All loads complete within the
// barrier interval, so the vmcnt(0) drain at __syncthreads is free.
__global__ __launch_bounds__(256, 3) void fused_main(
    const float* __restrict__ rep,
    const float* __restrict__ Pf,
    const float* __restrict__ Qf,
    const float* __restrict__ Rf,
    const unsigned short* __restrict__ W2f,
    const float* __restrict__ t2, const float* __restrict__ c2,
    const float* __restrict__ W3, const float* __restrict__ b3,
    float* __restrict__ out) {
  __shared__ unsigned short Abuf[2][2048];  // 2 x 4KB, frag-ordered
  __shared__ float QRs[1024];               // Q rows [0..511], R rows [512..1023]
  __shared__ float partial[4][64];

  const int t = threadIdx.x;
  const int w = t >> 6;
  const int ln = t & 15;
  const int lq = (t >> 4) & 3;
  const int k0 = blockIdx.x;
  const int bg = w * 16 + ln;

  // stage Q/R rows for k0 into LDS (4KB, once)
  if (t < 128) {
    int cs = t >> 3, i = (t & 7) * 4;
    *(f32x4*)(&QRs[cs * 32 + i]) = *(const f32x4*)(Qf + cs * 65536 + k0 * 32 + i);
  } else {
    int tt = t - 128;
    int cs = tt >> 3, i = (tt & 7) * 4;
    *(f32x4*)(&QRs[512 + cs * 32 + i]) = *(const f32x4*)(Rf + cs * 65536 + k0 * 32 + i);
  }

  const float rb = rep[bg * 2048 + k0];
  const float* pbase = Pf + bg * 32 + lq * 8;
  const unsigned short* wbase = W2f + (w * 64 + ln) * 32 + lq * 8;

  f32x4 acc[4][4];
  #pragma unroll
  for (int mi = 0; mi < 4; ++mi)
    #pragma unroll
    for (int nj = 0; nj < 4; ++nj) acc[mi][nj] = (f32x4){0.f, 0.f, 0.f, 0.f};

  // gen VALU + fragment-ordered LDS write for one chunk
  auto genw = [&](f32x4 pa, f32x4 pb, f32x4 qa, f32x4 qb, f32x4 ra, f32x4 rc, int bi) {
    unsigned u[8];
    #pragma unroll
    for (int j = 0; j < 4; ++j) {
      float z0 = fmaf(-rb, ra[j], pa[j] + qa[j]);
      float z1 = fmaf(-rb, rc[j], pb[j] + qb[j]);
      u[j]     = __float_as_uint(fmaxf(z0, 0.f)) + 0x8000u;
      u[j + 4] = __float_as_uint(fmaxf(z1, 0.f)) + 0x8000u;
    }
    unsigned d0 = __builtin_amdgcn_perm(u[1], u[0], 0x07060302);
    unsigned d1 = __builtin_amdgcn_perm(u[3], u[2], 0x07060302);
    unsigned d2 = __builtin_amdgcn_perm(u[5], u[4], 0x07060302);
    unsigned d3 = __builtin_amdgcn_perm(u[7], u[6], 0x07060302);
    *(uint4*)(&Abuf[bi][t * 8]) = make_uint4(d0, d1, d2, d3);
  };

  __syncthreads();  // QRs ready

  // P-input pipeline regs (2 sets, parity-indexed), B-frag double buffer
  f32x4 gpa[2], gpb[2];
  short8 bfr[2][4];

  // prologue: generate chunk 0 into Abuf[0]; preload P(1), bfr(0)
  {
    f32x4 pa = *(const f32x4*)(pbase);
    f32x4 pb = *(const f32x4*)(pbase + 4);
    const float* q = &QRs[lq * 8];
    const float* r = &QRs[512 + lq * 8];
    genw(pa, pb, *(const f32x4*)q, *(const f32x4*)(q + 4),
         *(const f32x4*)r, *(const f32x4*)(r + 4), 0);
  }
  gpa[1] = *(const f32x4*)(pbase + 2048);
  gpb[1] = *(const f32x4*)(pbase + 2048 + 4);
  #pragma unroll
  for (int nj = 0; nj < 4; ++nj)
    bfr[0][nj] = *(const short8*)(wbase + nj * 512);

  #pragma unroll
  for (int cs = 0; cs < 16; ++cs) {
    __syncthreads();  // Abuf[cs&1] ready
    // A-frags for chunk cs: issue first (latency shadowed by gen VALU below)
    const unsigned short* ab = Abuf[cs & 1];
    short8 afr[4];
    #pragma unroll
    for (int mi = 0; mi < 4; ++mi)
      afr[mi] = *(const short8*)(ab + ((mi * 4 + lq) * 16 + ln) * 8);
    // B-frags for chunk cs+1 (consumed next iter)
    if (cs < 15) {
      #pragma unroll
      for (int nj = 0; nj < 4; ++nj)
        bfr[(cs + 1) & 1][nj] = *(const short8*)(wbase + (cs + 1) * 8192 + nj * 512);
    }
    // P inputs for chunk cs+2 (consumed next iter)
    if (cs < 14) {
      gpa[cs & 1] = *(const f32x4*)(pbase + (cs + 2) * 2048);
      gpb[cs & 1] = *(const f32x4*)(pbase + (cs + 2) * 2048 + 4);
    }
    // gen chunk cs+1 from pipelined P + LDS Q/R
    if (cs < 15) {
      const float* q = &QRs[(cs + 1) * 32 + lq * 8];
      const float* r = &QRs[512 + (cs + 1) * 32 + lq * 8];
      genw(gpa[(cs & 1) ^ 1], gpb[(cs & 1) ^ 1],
           *(const f32x4*)q, *(const f32x4*)(q + 4),
           *(const f32x4*)r, *(const f32x4*)(r + 4), (cs + 1) & 1);
    }
    #pragma unroll
    for (int mi = 0; mi < 4; ++mi)
      #pragma unroll
      for (int nj = 0; nj < 4; ++nj)
        acc[mi][nj] = __builtin_amdgcn_mfma_f32_16x16x32_bf16(afr[mi], bfr[cs & 1][nj], acc[mi][nj], 0, 0, 0);
  }

  // epilogue: u = relu(t2[o]*acc + c2[o]) * W3[o]; reduce over o
  float t2v[4], c2v[4], w3v[4];
  #pragma unroll
  for (int nj = 0; nj < 4; ++nj) {
    int o = w * 64 + nj * 16 + ln;
    t2v[nj] = t2[o];
    c2v[nj] = c2[o];
    w3v[nj] = W3[o];
  }
  #pragma unroll
  for (int mi = 0; mi < 4; ++mi) {
    float s[4] = {0.f, 0.f, 0.f, 0.f};
    #pragma unroll
    for (int nj = 0; nj < 4; ++nj)
      #pragma unroll
      for (int r = 0; r < 4; ++r) {
        float u = fmaf(t2v[nj], acc[mi][nj][r], c2v[nj]);
        u = fmaxf(u, 0.f);
        s[r] = fmaf(u, w3v[nj], s[r]);
      }
    #pragma unroll
    for (int r = 0; r < 4; ++r) {
      #pragma unroll
      for (int m = 1; m < 16; m <<= 1) s[r] += __shfl_xor(s[r], m, 64);
    }
    if (ln == 0) {
      #pragma unroll
      for (int r = 0; r < 4; ++r) partial[w][mi * 16 + lq * 4 + r] = s[r];
    }
  }
  __syncthreads();
  if (t < 64) {
    out[t * 2048 + k0] =
        partial[0][t] + partial[1][t] + partial[2][t] + partial[3][t] + b3[0];
  }
}

extern "C" void kernel_launch(void* const* d_in, const int* in_sizes, int n_in,
                              void* d_out, int out_size, void* d_ws, size_t ws_size,
                              hipStream_t stream) {
  const float* rep   = (const float*)d_in[0];
  const float* emb   = (const float*)d_in[1];
  const float* W1    = (const float*)d_in[2];
  const float* b1    = (const float*)d_in[3];
  const float* g1    = (const float*)d_in[4];
  const float* beta1 = (const float*)d_in[5];
  const float* m1    = (const float*)d_in[6];
  const float* v1    = (const float*)d_in[7];
  const float* W2    = (const float*)d_in[8];
  const float* b2    = (const float*)d_in[9];
  const float* g2    = (const float*)d_in[10];
  const float* beta2 = (const float*)d_in[11];
  const float* m2    = (const float*)d_in[12];
  const float* v2    = (const float*)d_in[13];
  const float* W3    = (const float*)d_in[14];
  const float* b3    = (const float*)d_in[15];
  float* out = (float*)d_out;

  char* ws = (char*)d_ws;
  float* t2           = (float*)(ws + 0);        // 256 f32
  float* c2           = (float*)(ws + 1024);     // 256 f32
  float* Pf           = (float*)(ws + 4096);     // 16x64x32 f32 = 128 KB
  float* Qf           = (float*)(ws + 262144);   // 16x2048x32 f32 = 4 MB
  float* Rf           = (float*)(ws + 4456448);  // 4 MB
  unsigned short* W2f = (unsigned short*)(ws + 8650752);  // 16x256x32 bf16 = 256 KB

  prep<<<321, 256, 0, stream>>>(emb, W1, g1, v1, W2, g2, v2, b2, m2, beta2,
                                Qf, Rf, W2f, t2, c2);
  p_gemm<<<64, 1024, 0, stream>>>(rep, W1, g1, v1, b1, m1, beta1, Pf);
  fused_main<<<2048, 256, 0, stream>>>(rep, Pf, Qf, Rf, W2f, t2, c2, W3, b3, out);
}